// Round 7
// baseline (251.723 us; speedup 1.0000x reference)
//
#include <hip/hip_runtime.h>

// Problem constants: B=8, T=1024, C=1024, H=16, hs=64
#define TT 1024
#define CC 1024
#define NH 16
#define HS 64

typedef __attribute__((ext_vector_type(8))) short short8;
typedef __attribute__((ext_vector_type(4))) float f32x4;

// round-to-nearest-even fp32 -> bf16 bits (finite inputs)
__device__ inline unsigned short f2bf(float f) {
  unsigned int u = __float_as_uint(f);
  unsigned int r = u + 0x7FFFu + ((u >> 16) & 1u);
  return (unsigned short)(r >> 16);
}

// pack 2 f32 -> u32 of 2 bf16 (lo in low half), single HW instr
__device__ inline unsigned int cvtpk_bf16(float lo, float hi) {
  unsigned int r;
  asm("v_cvt_pk_bf16_f32 %0, %1, %2" : "=v"(r) : "v"(lo), "v"(hi));
  return r;
}

#define GLDS16(g, l)                                                         \
  __builtin_amdgcn_global_load_lds(                                          \
      (const __attribute__((address_space(1))) void*)(g),                    \
      (__attribute__((address_space(3))) void*)(l), 16, 0, 0)

// ---------------------------------------------------------------------------
// fp32 -> bf16 elementwise (4 per thread)
// ---------------------------------------------------------------------------
__global__ __launch_bounds__(256) void f32_to_bf16(
    const float* __restrict__ in, unsigned short* __restrict__ out, int n4) {
  int i = (blockIdx.x * 256 + threadIdx.x);
  if (i >= n4) return;
  float4 v = *(const float4*)&in[(size_t)i * 4];
  ushort4 o;
  o.x = f2bf(v.x); o.y = f2bf(v.y); o.z = f2bf(v.z); o.w = f2bf(v.w);
  *(ushort4*)&out[(size_t)i * 4] = o;
}

// ---------------------------------------------------------------------------
// W[K][N] fp32 -> Wt[N][K] bf16 (32x32 tiles via LDS)
// ---------------------------------------------------------------------------
__global__ __launch_bounds__(256) void transpose_to_bf16(
    const float* __restrict__ W, unsigned short* __restrict__ Wt,
    int K, int N) {
  __shared__ float tile[32][33];
  const int n0 = blockIdx.x * 32, k0 = blockIdx.y * 32;
  const int t = threadIdx.x;
  {
    const int kr = t >> 3;
    const int nc = (t & 7) * 4;
    float4 v = *(const float4*)&W[(size_t)(k0 + kr) * N + n0 + nc];
    tile[kr][nc + 0] = v.x; tile[kr][nc + 1] = v.y;
    tile[kr][nc + 2] = v.z; tile[kr][nc + 3] = v.w;
  }
  __syncthreads();
  {
    const int nr = t >> 3;
    const int kc = (t & 7) * 4;
    ushort4 o;
    o.x = f2bf(tile[kc + 0][nr]);
    o.y = f2bf(tile[kc + 1][nr]);
    o.z = f2bf(tile[kc + 2][nr]);
    o.w = f2bf(tile[kc + 3][nr]);
    *(ushort4*)&Wt[(size_t)(n0 + nr) * K + k0 + kc] = o;
  }
}

// ---------------------------------------------------------------------------
// 8-phase MFMA GEMM (T3+T4+T2+T5+T1): C = A @ Bt^T + bias.
// 256x256 tile, BK=64, 512 threads = 8 waves (2M x 4N), per-wave 128x64 out.
// LDS 128 KB dynamic: {A,B} x 2 dbuf x 2 halves of [128][64] bf16.
// Per K-tile 4 phases: ph0{12 ds_read -> 16 MFMA}, ph1{4 -> 16},
// ph2{stage B(t+2) | 8 -> 16}, ph3{stage A(t+2) -> 16}; barrier+lgkmcnt(0)
// +setprio around each MFMA cluster; counted vmcnt(8) once per K-tile.
// Ledger: tile tau staged at iter tau-2 into buf tau&1 (8 loads/thread/tile);
// at iter t ph0, vmcnt(8) retires exactly tile t's 8 (t+1's 8 stay in
// flight); last iter vmcnt(0). Write windows: B(t+2) after ph1 barrier
// (all B reads done), A(t+2) after ph2 barrier (all A reads done).
// Swizzle: 16B chunk c stored at c ^ (row&7) (inv-swz global source,
// fwd-swz ds_read) -> fragment column reads spread 8 rows over 8 chunk
// slots = 2 lanes/bank-quad = free.
// ---------------------------------------------------------------------------
template <bool BF16_OUT>
__global__ __launch_bounds__(512, 2) void gemm_8ph(
    const unsigned short* __restrict__ A,   // [M][K] bf16
    const unsigned short* __restrict__ Bt,  // [N][K] bf16
    const float* __restrict__ bias,         // [N] fp32
    void* __restrict__ Cv,                  // [M][N]
    int M, int N, int K) {
  extern __shared__ __attribute__((aligned(16))) unsigned short smg[];
  typedef __attribute__((address_space(3))) unsigned short lds_us;
  lds_us* sml = (lds_us*)smg;

  const int tid = threadIdx.x;
  const int w = tid >> 6, l = tid & 63;
  const int lr = l & 15, lg = l >> 4;
  const int wm = w >> 2, wn = w & 3;

  // T1: bijective XCD-contiguous remap (nwg % 8 == 0)
  const int gx = gridDim.x;
  const int nwg = gx * gridDim.y;
  int f = blockIdx.y * gx + blockIdx.x;
  f = (f & 7) * (nwg >> 3) + (f >> 3);
  const int bx = f % gx, by = f / gx;
  const int brow = by * 256, bcol = bx * 256;

  // --- staging geometry ---
  // round q in {0,1}: LDS chunk g = q*512 + w*64 + l; row r = g>>3 (64/round),
  // chunk c = l&7. Inverse-swizzled global chunk = c ^ (r&7) = (l&7)^(l>>3).
  const int r0 = w * 8 + (l >> 3);               // 0..63
  const int cs = (l & 7) ^ (l >> 3);             // global chunk
  const unsigned short* Asrc = A + (size_t)(brow + r0) * K + cs * 8;
  const unsigned short* Bsrc = Bt + (size_t)(bcol + r0) * K + cs * 8;
  const int wlds = w * 512;                       // wave-uniform LDS base part

  // A region: sml[0..32768), B region: sml[32768..65536) (ushort units)
  // (dbuf d, half h, round q): base = d*16384 + h*8192 + q*4096 + wlds
#define ST_A(dd, hh, qq, kt)                                                 \
  GLDS16(Asrc + (size_t)((hh)*128 + (qq)*64) * K + (kt) * 64,                \
         sml + (dd)*16384 + (hh)*8192 + (qq)*4096 + wlds)
#define ST_B(dd, hh, qq, kt)                                                 \
  GLDS16(Bsrc + (size_t)((hh)*128 + (qq)*64) * K + (kt) * 64,                \
         sml + 32768 + (dd)*16384 + (hh)*8192 + (qq)*4096 + wlds)

  f32x4 acc[8][4] = {};
  short8 afA[4][2], bfB[4][2];

  // fragment read offsets (within own half): row = mi*16+lr, chunk (ks*4+lg)
  // swizzled by ^(lr&7); elem off = row*64 + chunk*8
  const int ck0 = ((lg) ^ (lr & 7)) * 8;
  const int ck1 = ((4 | lg) ^ (lr & 7)) * 8;
  const int abase = wm * 8192 + lr * 64;          // + b*16384
  const int bbase = 32768 + (wn >> 1) * 8192 + (wn & 1) * 4096 + lr * 64;

#define LDA(MI0)                                                             \
  _Pragma("unroll") for (int mi = 0; mi < 4; ++mi) {                         \
    afA[mi][0] = *(const short8*)(smg + bb * 16384 + abase + ((MI0) + mi) * 1024 + ck0); \
    afA[mi][1] = *(const short8*)(smg + bb * 16384 + abase + ((MI0) + mi) * 1024 + ck1); \
  }
#define LDB(NI0)                                                             \
  _Pragma("unroll") for (int ni = 0; ni < 2; ++ni) {                         \
    bfB[(NI0) + ni][0] = *(const short8*)(smg + bb * 16384 + bbase + ((NI0) + ni) * 1024 + ck0); \
    bfB[(NI0) + ni][1] = *(const short8*)(smg + bb * 16384 + bbase + ((NI0) + ni) * 1024 + ck1); \
  }
#define MFMA_Q(MI0, NI0)                                                     \
  __builtin_amdgcn_s_setprio(1);                                             \
  _Pragma("unroll") for (int mi = 0; mi < 4; ++mi)                           \
  _Pragma("unroll") for (int ni = 0; ni < 2; ++ni)                           \
  _Pragma("unroll") for (int ks = 0; ks < 2; ++ks)                           \
    acc[(MI0) + mi][(NI0) + ni] = __builtin_amdgcn_mfma_f32_16x16x32_bf16(   \
        afA[mi][ks], bfB[(NI0) + ni][ks], acc[(MI0) + mi][(NI0) + ni], 0, 0, 0); \
  __builtin_amdgcn_s_setprio(0);
#define WAIT_LGKM                                                            \
  asm volatile("s_waitcnt lgkmcnt(0)" ::: "memory");                         \
  __builtin_amdgcn_sched_barrier(0);

  const int nk = K >> 6;   // K-tiles of 64

  // prologue: stage tile 0 -> buf0, tile 1 -> buf1 (8 loads each, in order)
#pragma unroll
  for (int tt = 0; tt < 2; ++tt) {
    ST_A(tt, 0, 0, tt); ST_A(tt, 0, 1, tt); ST_A(tt, 1, 0, tt); ST_A(tt, 1, 1, tt);
    ST_B(tt, 0, 0, tt); ST_B(tt, 0, 1, tt); ST_B(tt, 1, 0, tt); ST_B(tt, 1, 1, tt);
  }

  for (int t = 0; t < nk; ++t) {
    const int bb = t & 1;
    const bool dostage = (t + 2 < nk);
    // ---- ph0 ----
    if (t == nk - 1) { asm volatile("s_waitcnt vmcnt(0)" ::: "memory"); }
    else             { asm volatile("s_waitcnt vmcnt(8)" ::: "memory"); }
    __builtin_amdgcn_sched_barrier(0);
    __builtin_amdgcn_s_barrier();            // buf bb fully landed, visible
    LDA(0); LDB(0);                          // 12 ds_read_b128
    WAIT_LGKM;
    MFMA_Q(0, 0);
    __builtin_amdgcn_s_barrier();
    // ---- ph1 ----
    LDB(2);                                  // 4 ds_read
    WAIT_LGKM;
    MFMA_Q(0, 2);
    __builtin_amdgcn_s_barrier();            // all B(t) reads done -> B window
    // ---- ph2 ----
    if (dostage) { ST_B(bb, 0, 0, t + 2); ST_B(bb, 0, 1, t + 2);
                   ST_B(bb, 1, 0, t + 2); ST_B(bb, 1, 1, t + 2); }
    LDA(4);                                  // 8 ds_read
    WAIT_LGKM;
    MFMA_Q(4, 0);
    __builtin_amdgcn_s_barrier();            // all A(t) reads done -> A window
    // ---- ph3 ----
    if (dostage) { ST_A(bb, 0, 0, t + 2); ST_A(bb, 0, 1, t + 2);
                   ST_A(bb, 1, 0, t + 2); ST_A(bb, 1, 1, t + 2); }
    MFMA_Q(4, 2);
    __builtin_amdgcn_s_barrier();
  }
#undef ST_A
#undef ST_B
#undef LDA
#undef LDB
#undef MFMA_Q
#undef WAIT_LGKM

  // epilogue: C/D layout col=lane&15, row=(lane>>4)*4+j
#pragma unroll
  for (int ni = 0; ni < 4; ++ni) {
    const int col = bcol + wn * 64 + ni * 16 + lr;
    const float bv = bias[col];
#pragma unroll
    for (int mi = 0; mi < 8; ++mi) {
      const int row0 = brow + wm * 128 + mi * 16 + lg * 4;
#pragma unroll
      for (int j = 0; j < 4; ++j) {
        const float val = acc[mi][ni][j] + bv;
        if (BF16_OUT)
          ((unsigned short*)Cv)[(size_t)(row0 + j) * N + col] = f2bf(val);
        else
          ((float*)Cv)[(size_t)(row0 + j) * N + col] = val;
      }
    }
  }
}

// ---------------------------------------------------------------------------
// MFMA GEMM (round-6 structure, kept for proj): 256x128 tile, BK=32, 8 waves.
// ---------------------------------------------------------------------------
template <bool BF16_OUT>
__global__ __launch_bounds__(512, 4) void gemm_bt_256(
    const unsigned short* __restrict__ A,   // [M][K] bf16
    const unsigned short* __restrict__ Bt,  // [N][K] bf16
    const float* __restrict__ bias,         // [N] fp32
    void* __restrict__ Cv,                  // [M][N]
    int M, int N, int K) {
  __shared__ __attribute__((aligned(16))) unsigned short As[2][256 * 32];
  __shared__ __attribute__((aligned(16))) unsigned short Bs[2][128 * 32];

  const int tid = threadIdx.x;
  const int w = tid >> 6, l = tid & 63;
  const int lr = l & 15, lg = l >> 4;
  const int wr = w >> 1, wc = w & 1;

  const int gx = gridDim.x;
  const int nwg = gx * gridDim.y;
  int f = blockIdx.y * gx + blockIdx.x;
  f = (f & 7) * (nwg >> 3) + (f >> 3);
  const int bx = f % gx, by = f / gx;
  const int brow = by * 256, bcol = bx * 128;

  const int ga0 = tid, ga1 = 512 + tid;
  const int ar0 = ga0 >> 2, ac0 = ga0 & 3;
  const int ar1 = ga1 >> 2, ac1 = ga1 & 3;
  const int br_ = tid >> 2, bc_ = tid & 3;
  const unsigned short* Asrc0 =
      A + (size_t)(brow + ar0) * K + (ac0 ^ ((ar0 >> 1) & 3)) * 8;
  const unsigned short* Asrc1 =
      A + (size_t)(brow + ar1) * K + (ac1 ^ ((ar1 >> 1) & 3)) * 8;
  const unsigned short* Bsrc =
      Bt + (size_t)(bcol + br_) * K + (bc_ ^ ((br_ >> 1) & 3)) * 8;

  typedef __attribute__((address_space(3))) unsigned short lds_us;

#define STAGE(bb, kt)                                                        \
  do {                                                                       \
    const int k0_ = (kt) * 32;                                               \
    GLDS16(Asrc0 + k0_, (lds_us*)&As[bb][0] + ga0 * 8);                      \
    GLDS16(Asrc1 + k0_, (lds_us*)&As[bb][0] + ga1 * 8);                      \
    GLDS16(Bsrc + k0_, (lds_us*)&Bs[bb][0] + tid * 8);                       \
  } while (0)

  f32x4 acc[4][4] = {};

  const int sfr = ((((lr >> 1) & 3) ^ lg) * 8);
  const int arow0 = wr * 64 + lr;
  const int brow0 = wc * 64 + lr;

#define KSTEP(cur, kt, VMASM, DOSTAGE)                                       \
  do {                                                                       \
    asm volatile(VMASM ::: "memory");                                        \
    __builtin_amdgcn_sched_barrier(0);                                       \
    __builtin_amdgcn_s_barrier();                                            \
    short8 af[4], bf[4];                                                     \
    _Pragma("unroll") for (int mi_ = 0; mi_ < 4; ++mi_)                      \
        af[mi_] = *(const short8*)&As[cur][(arow0 + mi_ * 16) * 32 + sfr];   \
    _Pragma("unroll") for (int ni_ = 0; ni_ < 4; ++ni_)                      \
        bf[ni_] = *(const short8*)&Bs[cur][(brow0 + ni_ * 16) * 32 + sfr];   \
    asm volatile("s_waitcnt lgkmcnt(0)" ::: "memory");                       \
    __builtin_amdgcn_sched_barrier(0);                                       \
    __builtin_amdgcn_s_barrier();                                            \
    __builtin_amdgcn_sched_barrier(0);                                       \
    if (DOSTAGE) STAGE(cur, (kt) + 2);                                       \
    __builtin_amdgcn_s_setprio(1);                                           \
    _Pragma("unroll") for (int mi_ = 0; mi_ < 4; ++mi_)                      \
        _Pragma("unroll") for (int ni_ = 0; ni_ < 4; ++ni_)                  \
            acc[mi_][ni_] = __builtin_amdgcn_mfma_f32_16x16x32_bf16(         \
                af[mi_], bf[ni_], acc[mi_][ni_], 0, 0, 0);                   \
    __builtin_amdgcn_s_setprio(0);                                           \
  } while (0)

  const int nk = K >> 5;
  STAGE(0, 0);
  STAGE(1, 1);
  int cur = 0;
  for (int t = 0; t < nk - 1; ++t) {
    KSTEP(cur, t, "s_waitcnt vmcnt(3)", (t + 2 < nk));
    cur ^= 1;
  }
  KSTEP(cur, nk - 1, "s_waitcnt vmcnt(0)", false);
#undef KSTEP
#undef STAGE

#pragma unroll
  for (int ni = 0; ni < 4; ++ni) {
    const int col = bcol + wc * 64 + ni * 16 + lr;
    const float bv = bias[col];
#pragma unroll
    for (int mi = 0; mi < 4; ++mi) {
      const int row0 = brow + wr * 64 + mi * 16 + lg * 4;
#pragma unroll
      for (int j = 0; j < 4; ++j) {
        const float val = acc[mi][ni][j] + bv;
        if (BF16_OUT)
          ((unsigned short*)Cv)[(size_t)(row0 + j) * N + col] = f2bf(val);
        else
          ((float*)Cv)[(size_t)(row0 + j) * N + col] = val;
      }
    }
  }
}

// ---------------------------------------------------------------------------
// MFMA flash attention, causal, swapped operands (S^T / O^T), no-max softmax.
// ---------------------------------------------------------------------------
#define C1 0.18033688f  // 0.125 * log2(e)

__global__ __launch_bounds__(256) void attn_mfma(
    const unsigned short* __restrict__ qkv, unsigned short* __restrict__ aout) {
  const int bh = blockIdx.y;
  const int b = bh >> 4, h = bh & 15;
  const int tid = threadIdx.x;
  const int w = tid >> 6;
  const int l = tid & 63;
  const int lr = l & 15;
  const int lg = l >> 4;

  __shared__ __attribute__((aligned(16))) unsigned short Kl[64 * 64];
  __shared__ __attribute__((aligned(16))) unsigned short Vt[64 * 64];
  __shared__ __attribute__((aligned(16))) unsigned short Pq[4][32 * 64];

  const size_t row3c = 3 * CC;
  const unsigned short* qbase = qkv + (size_t)(b * TT) * row3c + h * HS;
  const unsigned short* kbase = qbase + CC;
  const unsigned short* vbase = qbase + 2 * CC;

  const int ksrow = 16 * w + (l >> 3);
  const int ksbyte = (((l & 7) ^ (l >> 3)) << 4);
  typedef __attribute__((address_space(3))) unsigned short lds_us;
  lds_us* KlW0 = (lds_us*)Kl + (16 * w) * 64;
  lds_us* KlW1 = (lds_us*)Kl + (16 * w + 8) * 64;

#pragma unroll 1
  for (int pass = 0; pass < 2; ++pass) {
    const int qt = pass ? (7 - blockIdx.x) : blockIdx.x;
    const int qw = qt * 128 + w * 32;

    short8 aq[2][2];
#pragma unroll
    for (int mi = 0; mi < 2; ++mi)
#pragma unroll
      for (int ks = 0; ks < 2; ++ks)
        aq[mi][ks] = *(const short8*)(qbase +
            (size_t)(qw + mi * 16 + lr) * row3c + ks * 32 + lg * 8);

    f32x4 sOT[4][2] = {};
    float lpart[2] = {0.f, 0.f};

    const int ntiles = 2 * qt + 2;
    for (int kt = 0; kt < ntiles; ++kt) {
      const int k0 = kt * 64;
      GLDS16((const char*)(kbase + (size_t)(k0 + ksrow) * row3c) + ksbyte, KlW0);
      GLDS16((const char*)(kbase + (size_t)(k0 + 8 + ksrow) * row3c) + ksbyte, KlW1);
      {
        const unsigned short* vsrc = vbase + (size_t)(k0 + l) * row3c + 16 * w;
        short8 v0 = *(const short8*)(vsrc);
        short8 v1 = *(const short8*)(vsrc + 8);
#pragma unroll
        for (int i = 0; i < 8; ++i) {
          const int d0 = 16 * w + i, d1 = d0 + 8;
          Vt[(d0 * 64 + l) ^ ((d0 & 7) << 3)] = (unsigned short)v0[i];
          Vt[(d1 * 64 + l) ^ ((d1 & 7) << 3)] = (unsigned short)v1[i];
        }
      }
      __syncthreads();

      if (k0 <= qw + 31) {
        f32x4 sacc[4][2] = {};
        short8 ak[4][2];
#pragma unroll
        for (int ni = 0; ni < 4; ++ni) {
          const int tok = ni * 16 + lr;
          const int sw = (tok & 7) << 3;
#pragma unroll
          for (int ks = 0; ks < 2; ++ks)
            ak[ni][ks] = *(const short8*)&Kl[tok * 64 + ((ks * 32 + lg * 8) ^ sw)];
        }
#pragma unroll
        for (int ni = 0; ni < 4; ++ni)
#pragma unroll
          for (int mi = 0; mi < 2; ++mi)
#pragma unroll
            for (int ks = 0; ks < 2; ++ks)
              sacc[ni][mi] = __builtin_amdgcn_mfma_f32_16x16x32_bf16(
                  ak[ni][ks], aq[mi][ks], sacc[ni][mi], 0, 0, 0);

        const bool diag = (k0 + 63 > qw);
#pragma unroll
        for (int mi = 0; mi < 2; ++mi) {
          const int qloc = mi * 16 + lr;
          const int qglob = qw + qloc;
          const int psw = (qloc & 7) << 3;
          float ls = 0.f;
#pragma unroll
          for (int ni = 0; ni < 4; ++ni) {
            float p[4];
#pragma unroll
            for (int jj = 0; jj < 4; ++jj) {
              const float pv = exp2f(fmaf(sacc[ni][mi][jj], C1, -2.0f));
              const int kvg = k0 + ni * 16 + lg * 4 + jj;
              p[jj] = (diag && (kvg > qglob)) ? 0.f : pv;
            }
            ls += (p[0] + p[1]) + (p[2] + p[3]);
            uint2 pk;
            pk.x = cvtpk_bf16(p[0], p[1]);
            pk.y = cvtpk_bf16(p[2], p[3]);
            *(uint2*)&Pq[w][qloc * 64 + ((ni * 16 + lg * 4) ^ psw)] = pk;
          }
          lpart[mi] += ls;
        }

        short8 av[4][2], bp[2][2];
#pragma unroll
        for (int nd = 0; nd < 4; ++nd) {
          const int d = nd * 16 + lr;
          const int sw = (d & 7) << 3;
#pragma unroll
          for (int ks = 0; ks < 2; ++ks)
            av[nd][ks] = *(const short8*)&Vt[d * 64 + ((ks * 32 + lg * 8) ^ sw)];
        }
#pragma unroll
        for (int mi = 0; mi < 2; ++mi) {
          const int qloc = mi * 16 + lr;
          const int psw = (qloc & 7) << 3;
#pragma unroll
          for (int ks = 0; ks < 2; ++ks)
            bp[mi][ks] = *(const short8*)&Pq[w][qloc * 64 + ((ks * 32 + lg * 8) ^ psw)];
        }
#pragma unroll
        for (int nd = 0; nd < 4; ++nd)
#pragma unroll
          for (int mi = 0; mi < 2; ++mi)
#pragma unroll
            for (int ks = 0; ks < 2; ++ks)
              sOT[nd][mi] = __builtin_amdgcn_mfma_f32_16x16x32_bf16(
                  av[nd][ks], bp[mi][ks], sOT[nd][mi], 0, 0, 0);
      }
      __syncthreads();
    }

#pragma unroll
    for (int mi = 0; mi < 2; ++mi) {
      float ls = lpart[mi];
      ls += __shfl_xor(ls, 16);
      ls += __shfl_xor(ls, 32);
      const float inv = 1.f / ls;
      const size_t row = (size_t)(b * TT + qw + mi * 16 + lr);
#pragma unroll
      for (int nd = 0; nd < 4; ++nd) {
        uint2 pk;
        pk.x = cvtpk_bf16(sOT[nd][mi][0] * inv, sOT[nd][mi][1] * inv);
        pk.y = cvtpk_bf16(sOT[nd][mi][2] * inv, sOT[nd][mi][3] * inv);
        *(uint2*)&aout[row * CC + h * HS + nd * 16 + lg * 4] = pk;
      }
    }
  }
}

// ---------------------------------------------------------------------------
extern "C" void kernel_launch(void* const* d_in, const int* in_sizes, int n_in,
                              void* d_out, int out_size, void* d_ws, size_t ws_size,
                              hipStream_t stream) {
  const float* x     = (const float*)d_in[0];
  const float* Wqkv  = (const float*)d_in[1];
  const float* bqkv  = (const float*)d_in[2];
  const float* Wproj = (const float*)d_in[3];
  const float* bproj = (const float*)d_in[4];
  float* out = (float*)d_out;

  char* ws = (char*)d_ws;
  unsigned short* qkvb   = (unsigned short*)ws;                    // 48 MB
  unsigned short* xb     = (unsigned short*)(ws + 50331648);       // 16 MB
  unsigned short* attnb  = (unsigned short*)(ws + 67108864);       // 16 MB
  unsigned short* wqkvt  = (unsigned short*)(ws + 83886080);       // 6 MB
  unsigned short* wprojt = (unsigned short*)(ws + 90177536);       // 2 MB

  const int M = 8 * TT;  // 8192

  // allow 128 KB dynamic LDS for the 8-phase GEMM (idempotent, host-side)
  (void)hipFuncSetAttribute((const void*)&gemm_8ph<true>,
      hipFuncAttributeMaxDynamicSharedMemorySize, 131072);

  f32_to_bf16<<<dim3(8192), dim3(256), 0, stream>>>(x, xb, M * CC / 4);
  transpose_to_bf16<<<dim3(96, 32), dim3(256), 0, stream>>>(Wqkv, wqkvt, CC, 3 * CC);
  transpose_to_bf16<<<dim3(32, 32), dim3(256), 0, stream>>>(Wproj, wprojt, CC, CC);

  // 1) qkv (bf16 out): 8-phase GEMM, grid 12 x 32 = 384 blocks (%8==0)
  gemm_8ph<true><<<dim3(3 * CC / 256, M / 256), dim3(512), 131072, stream>>>(
      xb, wqkvt, bqkv, qkvb, M, 3 * CC, CC);

  // 2) causal MFMA attention -> bf16
  attn_mfma<<<dim3(4, 8 * NH), dim3(256), 0, stream>>>(qkvb, attnb);

  // 3) out = attn @ W_proj + b_proj (fp32 out): round-6 GEMM, 256 blocks
  gemm_bt_256<false><<<dim3(CC / 128, M / 256), dim3(512), 0, stream>>>(
      attnb, wprojt, bproj, out, M, CC, CC);
}